// Round 5
// baseline (16.792 us; speedup 1.0000x reference)
//
#include <hip/hip_runtime.h>

// StructuredPerceptron: B=32, S=2048, T=512
// loss = sum_b max(pred_score_b - gold_score_b, 0)
// score_b = sum_{s<L} unary[b,s,tag[s]] + sum_{1<=s<L} binary[tag[s-1],tag[s]]
// L = sum_s mask[b,s]
//
// Single graph node. Latency-bound: the optimization target is the serial
// dependency chain, not bandwidth. Pipeline:
//   1. prefetch coalesced streams (mask/tags/preds) -> registers
//   2. issue ALL scattered unary/binary gathers unconditionally (addresses
//      depend only on tags, NOT on L)
//   3. mask-reduce -> L while gathers are in flight
//   4. predicated accumulate from registers, block reduce
//   5. publish (G,P); last block (device counter, restored to 0 for graph
//      replay) serially sums ReLU'd losses -> out[0]. Deterministic order.

#define BB 32
#define SS 2048
#define TT 512

__device__ int sp_counter = 0;  // invariant: ==0 whenever no kernel in flight

__global__ __launch_bounds__(256) void sp_fused_kernel(
    const float* __restrict__ unary,
    const float* __restrict__ binary,
    const int*   __restrict__ tags,
    const int*   __restrict__ pred,
    const int*   __restrict__ mask,
    float*       __restrict__ ws,
    float*       __restrict__ out)
{
    const int b    = blockIdx.x;
    const int tid  = threadIdx.x;
    const int wave = tid >> 6;

    __shared__ int   s_ipart[4];
    __shared__ float s_part[8];
    __shared__ int   s_len;

    // ---- 1. prefetch coalesced streams ----
    int mk[8], tg[8], tp[8], tg0[8], tp0[8];
    #pragma unroll
    for (int k = 0; k < 8; ++k) {
        const int s    = tid + k * 256;
        const int base = b * SS + s;
        mk[k]  = mask[base];
        tg[k]  = tags[base];
        tp[k]  = pred[base];
        tg0[k] = (s >= 1) ? tags[base - 1] : 0;
        tp0[k] = (s >= 1) ? pred[base - 1] : 0;
    }

    // ---- 2. issue ALL scattered gathers unconditionally ----
    float vg[8], vp[8];
    #pragma unroll
    for (int k = 0; k < 8; ++k) {
        const int s    = tid + k * 256;
        const int base = b * SS + s;
        float g = unary[base * TT + tg[k]];
        float p = unary[base * TT + tp[k]];
        if (s >= 1) {
            g += binary[tg0[k] * TT + tg[k]];
            p += binary[tp0[k] * TT + tp[k]];
        }
        vg[k] = g;
        vp[k] = p;
    }

    // ---- 3. seq_len reduce (overlaps in-flight gathers) ----
    int m = 0;
    #pragma unroll
    for (int k = 0; k < 8; ++k) m += mk[k];
    #pragma unroll
    for (int off = 32; off > 0; off >>= 1) m += __shfl_down(m, off);
    if ((tid & 63) == 0) s_ipart[wave] = m;
    __syncthreads();
    if (tid == 0) s_len = s_ipart[0] + s_ipart[1] + s_ipart[2] + s_ipart[3];
    __syncthreads();
    const int L = s_len;

    // ---- 4. predicated accumulate + block reduce ----
    float g = 0.f, p = 0.f;
    #pragma unroll
    for (int k = 0; k < 8; ++k) {
        const int s = tid + k * 256;
        if (s < L) { g += vg[k]; p += vp[k]; }
    }
    #pragma unroll
    for (int off = 32; off > 0; off >>= 1) {
        g += __shfl_down(g, off);
        p += __shfl_down(p, off);
    }
    if ((tid & 63) == 0) { s_part[wave * 2] = g; s_part[wave * 2 + 1] = p; }
    __syncthreads();

    // ---- 5. publish + last-block finish ----
    if (tid == 0) {
        const float G = s_part[0] + s_part[2] + s_part[4] + s_part[6];
        const float P = s_part[1] + s_part[3] + s_part[5] + s_part[7];
        ws[2 * b]     = G;
        ws[2 * b + 1] = P;
        __threadfence();                        // publish ws before arrival
        const int old = atomicAdd(&sp_counter, 1);
        if (old == BB - 1) {                    // last block: finish
            __threadfence();                    // acquire all ws writes
            float total = 0.f;
            for (int i = 0; i < BB; ++i) {      // fixed order -> deterministic
                const float Gi = ws[2 * i];
                const float Pi = ws[2 * i + 1];
                total += fmaxf(Pi - Gi, 0.f);
            }
            out[0] = total;
            atomicExch(&sp_counter, 0);         // restore invariant for replay
        }
    }
}

extern "C" void kernel_launch(void* const* d_in, const int* in_sizes, int n_in,
                              void* d_out, int out_size, void* d_ws, size_t ws_size,
                              hipStream_t stream) {
    const float* unary  = (const float*)d_in[0];
    const float* binary = (const float*)d_in[1];
    const int*   tags   = (const int*)d_in[2];
    const int*   pred   = (const int*)d_in[3];
    const int*   mask   = (const int*)d_in[4];
    float* ws  = (float*)d_ws;
    float* out = (float*)d_out;

    sp_fused_kernel<<<BB, 256, 0, stream>>>(unary, binary, tags, pred, mask, ws, out);
}

// Round 6
// 14.034 us; speedup vs baseline: 1.1966x; 1.1966x over previous
//
#include <hip/hip_runtime.h>

// StructuredPerceptron: B=32, S=2048, T=512
// loss = sum_b max(pred_score_b - gold_score_b, 0)
// score_b = sum_{s<L} unary[b,s,tag[s]] + sum_{1<=s<L} binary[tag[s-1],tag[s]]
// L = sum_s mask[b,s]
//
// R5 lesson: the kernel is scattered-request SERVICE-bound, and 32 blocks
// use only 32 of 256 CUs' outstanding-request capacity. This version
// splits each batch into 8 slices -> 256 blocks -> 8x the memory-level
// parallelism for the ~66K predicated scattered gathers. Each block
// redundantly computes L from the full 8KB mask row (L3-hot, cheap).
// Single graph node; last block (device counter, restored to 0 for graph
// replay) does a parallel deterministic finish.

#define BB 32
#define SS 2048
#define TT 512
#define SLICES 8
#define NBLK (BB * SLICES)   // 256

__device__ int sp_counter = 0;  // invariant: ==0 whenever no kernel in flight

__global__ __launch_bounds__(256) void sp_fused_kernel(
    const float* __restrict__ unary,
    const float* __restrict__ binary,
    const int*   __restrict__ tags,
    const int*   __restrict__ pred,
    const int*   __restrict__ mask,
    float*       __restrict__ ws,
    float*       __restrict__ out)
{
    const int blk   = blockIdx.x;        // 0..255
    const int b     = blk >> 3;          // batch
    const int slice = blk & 7;           // slice within batch
    const int tid   = threadIdx.x;
    const int wave  = tid >> 6;
    const int s     = slice * 256 + tid; // this thread's position
    const int base  = b * SS + s;

    __shared__ int   s_ipart[4];
    __shared__ float s_part[8];
    __shared__ int   s_len;
    __shared__ int   s_last;

    // ---- 1. prefetch this position's coalesced tag data ----
    const int tg  = tags[base];
    const int tp  = pred[base];
    const int tg0 = (s >= 1) ? tags[base - 1] : 0;
    const int tp0 = (s >= 1) ? pred[base - 1] : 0;

    // ---- 2. L = sum(mask[b,:]) — full row, redundant per slice (L3-hot) ----
    int m = 0;
    #pragma unroll
    for (int k = 0; k < 8; ++k) m += mask[b * SS + tid + k * 256];
    #pragma unroll
    for (int off = 32; off > 0; off >>= 1) m += __shfl_down(m, off);
    if ((tid & 63) == 0) s_ipart[wave] = m;
    __syncthreads();
    if (tid == 0) s_len = s_ipart[0] + s_ipart[1] + s_ipart[2] + s_ipart[3];
    __syncthreads();
    const int L = s_len;

    // ---- 3. predicated scattered gathers (1 position / thread) ----
    float g = 0.f, p = 0.f;
    if (s < L) {
        g = unary[base * TT + tg];
        p = unary[base * TT + tp];
        if (s >= 1) {
            g += binary[tg0 * TT + tg];
            p += binary[tp0 * TT + tp];
        }
    }

    // ---- 4. block reduce (G,P) for this slice ----
    #pragma unroll
    for (int off = 32; off > 0; off >>= 1) {
        g += __shfl_down(g, off);
        p += __shfl_down(p, off);
    }
    if ((tid & 63) == 0) { s_part[wave * 2] = g; s_part[wave * 2 + 1] = p; }
    __syncthreads();

    // ---- 5. publish slice partial; last block finishes ----
    if (tid == 0) {
        const float G = s_part[0] + s_part[2] + s_part[4] + s_part[6];
        const float P = s_part[1] + s_part[3] + s_part[5] + s_part[7];
        ws[2 * blk]     = G;
        ws[2 * blk + 1] = P;
        __threadfence();                         // publish before arrival
        const int old = atomicAdd(&sp_counter, 1);
        s_last = (old == NBLK - 1);
    }
    __syncthreads();

    if (s_last) {
        __threadfence();                         // acquire all ws writes
        if (tid < BB) {                          // lane b -> batch b
            float G = 0.f, P = 0.f;
            #pragma unroll
            for (int sl = 0; sl < SLICES; ++sl) { // fixed order -> deterministic
                G += ws[2 * (tid * SLICES + sl)];
                P += ws[2 * (tid * SLICES + sl) + 1];
            }
            float loss = fmaxf(P - G, 0.f);
            #pragma unroll
            for (int off = 16; off > 0; off >>= 1) loss += __shfl_down(loss, off);
            if (tid == 0) {
                out[0] = loss;
                atomicExch(&sp_counter, 0);      // restore invariant for replay
            }
        }
    }
}

extern "C" void kernel_launch(void* const* d_in, const int* in_sizes, int n_in,
                              void* d_out, int out_size, void* d_ws, size_t ws_size,
                              hipStream_t stream) {
    const float* unary  = (const float*)d_in[0];
    const float* binary = (const float*)d_in[1];
    const int*   tags   = (const int*)d_in[2];
    const int*   pred   = (const int*)d_in[3];
    const int*   mask   = (const int*)d_in[4];
    float* ws  = (float*)d_ws;
    float* out = (float*)d_out;

    sp_fused_kernel<<<NBLK, 256, 0, stream>>>(unary, binary, tags, pred, mask, ws, out);
}

// Round 7
// 11.115 us; speedup vs baseline: 1.5108x; 1.2626x over previous
//
#include <hip/hip_runtime.h>

// StructuredPerceptron: B=32, S=2048, T=512
// loss = sum_b max(pred_score_b - gold_score_b, 0)
// score_b = sum_{s<L} unary[b,s,tag[s]] + sum_{1<=s<L} binary[tag[s-1],tag[s]]
// L = sum_s mask[b,s]
//
// R6 lesson: in-kernel 256-way counter sync costs ~+3us (serialized atomics
// + device fences + cross-XCD ws pulls). R1-vs-R3 lesson: an extra kernel
// NODE is ~free. So: wide gather kernel (256 blocks, max memory-level
// parallelism for the scattered loads, NO atomics/fences) + tiny finish
// kernel; the kernel boundary provides the device-scope sync for free.

#define BB 32
#define SS 2048
#define TT 512
#define SLICES 8
#define NBLK (BB * SLICES)   // 256

__global__ __launch_bounds__(256) void sp_gather_kernel(
    const float* __restrict__ unary,
    const float* __restrict__ binary,
    const int*   __restrict__ tags,
    const int*   __restrict__ pred,
    const int*   __restrict__ mask,
    float*       __restrict__ ws)
{
    const int blk   = blockIdx.x;        // 0..255
    const int b     = blk >> 3;          // batch
    const int slice = blk & 7;           // slice within batch
    const int tid   = threadIdx.x;
    const int wave  = tid >> 6;
    const int s     = slice * 256 + tid; // this thread's position
    const int base  = b * SS + s;

    __shared__ int   s_ipart[4];
    __shared__ float s_part[8];
    __shared__ int   s_len;

    // ---- prefetch this position's coalesced tag data ----
    const int tg  = tags[base];
    const int tp  = pred[base];
    const int tg0 = (s >= 1) ? tags[base - 1] : 0;
    const int tp0 = (s >= 1) ? pred[base - 1] : 0;

    // ---- L = sum(mask[b,:]) — full row, redundant per slice (L3-hot) ----
    int m = 0;
    #pragma unroll
    for (int k = 0; k < 8; ++k) m += mask[b * SS + tid + k * 256];
    #pragma unroll
    for (int off = 32; off > 0; off >>= 1) m += __shfl_down(m, off);
    if ((tid & 63) == 0) s_ipart[wave] = m;
    __syncthreads();
    if (tid == 0) s_len = s_ipart[0] + s_ipart[1] + s_ipart[2] + s_ipart[3];
    __syncthreads();
    const int L = s_len;

    // ---- predicated scattered gathers (1 position / thread) ----
    float g = 0.f, p = 0.f;
    if (s < L) {
        g = unary[base * TT + tg];
        p = unary[base * TT + tp];
        if (s >= 1) {
            g += binary[tg0 * TT + tg];
            p += binary[tp0 * TT + tp];
        }
    }

    // ---- block reduce (G,P) for this slice ----
    #pragma unroll
    for (int off = 32; off > 0; off >>= 1) {
        g += __shfl_down(g, off);
        p += __shfl_down(p, off);
    }
    if ((tid & 63) == 0) { s_part[wave * 2] = g; s_part[wave * 2 + 1] = p; }
    __syncthreads();

    if (tid == 0) {
        ws[2 * blk]     = s_part[0] + s_part[2] + s_part[4] + s_part[6];
        ws[2 * blk + 1] = s_part[1] + s_part[3] + s_part[5] + s_part[7];
    }
}

__global__ __launch_bounds__(64) void sp_finish_kernel(
    const float* __restrict__ ws, float* __restrict__ out)
{
    const int tid = threadIdx.x;
    float loss = 0.f;
    if (tid < BB) {
        float G = 0.f, P = 0.f;
        #pragma unroll
        for (int sl = 0; sl < SLICES; ++sl) {    // fixed order -> deterministic
            G += ws[2 * (tid * SLICES + sl)];
            P += ws[2 * (tid * SLICES + sl) + 1];
        }
        loss = fmaxf(P - G, 0.f);
    }
    #pragma unroll
    for (int off = 16; off > 0; off >>= 1) loss += __shfl_down(loss, off);
    if (tid == 0) out[0] = loss;
}

extern "C" void kernel_launch(void* const* d_in, const int* in_sizes, int n_in,
                              void* d_out, int out_size, void* d_ws, size_t ws_size,
                              hipStream_t stream) {
    const float* unary  = (const float*)d_in[0];
    const float* binary = (const float*)d_in[1];
    const int*   tags   = (const int*)d_in[2];
    const int*   pred   = (const int*)d_in[3];
    const int*   mask   = (const int*)d_in[4];
    float* ws  = (float*)d_ws;
    float* out = (float*)d_out;

    sp_gather_kernel<<<NBLK, 256, 0, stream>>>(unary, binary, tags, pred, mask, ws);
    sp_finish_kernel<<<1, 64, 0, stream>>>(ws, out);
}